// Round 3
// baseline (162.001 us; speedup 1.0000x reference)
//
#include <hip/hip_runtime.h>
#include <hip/hip_bf16.h>

// Problem: p1,p2 : (B=2, C=32, D=H=W=64) fp32. Pool 4x4x4 -> S=16.
// N = B*S^3 = 8192 rows of C=32. loss = ||A Aᵀ - B Bᵀ||_F² / N²
//           = (||AᵀA||² - 2||AᵀB||² + ||BᵀB||²) / N²  with 32x32 Grams only.
//
// v4: STREAMING pool. Previous versions gathered 64 scattered 1KiB chunks
// per block (3.1 TB/s wall, invariant to occupancy/ILP). Now each block
// reads one fully contiguous 256KiB span (one channel volume's 16 z-planes)
// — D2D-copy shaped, which this chip serves at ~6.3 TB/s.
// Pool structure falls out of the linear layout:
//   * thread's float4 = one complete x-group (4 consecutive x)
//   * 4 consecutive z-planes reduce in-thread
//   * the 4-row y-group = one wave -> 2x shfl_xor
// Pooled rows -> [row][c] global (2 MiB); tiny gram kernel finishes.

#define HW    4096      // 64*64
#define DHW   262144    // 64*64*64
#define NROW  8192
#define C     32
#define NPART 16        // partial Gram copies (atomic-contention spreading)

// ---------------------------------------------------------------------------
// Kernel 1: streaming 4x4x4 avg-pool (no normalize — that needs all
// channels; it's folded into gram staging).
// grid = 512 : (sel, b, c, slab). 1024 threads = 16 waves.
// Block reads vol[slab*16 .. slab*16+16) z-planes contiguously: 256KiB.
// Two half-passes of 8 planes each (keeps VGPRs ~64 for 2 blocks/CU).
// ---------------------------------------------------------------------------
__global__ __launch_bounds__(1024) void pool_kernel(
    const float* __restrict__ p1, const float* __restrict__ p2,
    float* __restrict__ A, float* __restrict__ B)
{
    const int bid  = blockIdx.x;
    const int slab = bid & 3;
    const int c    = (bid >> 2) & 31;
    const int b    = (bid >> 7) & 1;
    const int sel  = bid >> 8;

    const float* __restrict__ src = sel ? p2 : p1;
    float* __restrict__ dst       = sel ? B : A;

    const int tid  = threadIdx.x;
    const int wv   = tid >> 6;       // wave id == yo (0..15)
    const int lane = tid & 63;       // (y&3)*16 + x4

    const float* vol = src + (size_t)(b * C + c) * DHW + (size_t)(slab * 16) * HW;

    #pragma unroll
    for (int h = 0; h < 2; ++h) {
        // ---- 8 back-to-back contiguous wave-loads (1KiB each)
        float4 v[8];
        #pragma unroll
        for (int rz = 0; rz < 8; ++rz)
            v[rz] = *reinterpret_cast<const float4*>(
                        vol + (size_t)(h * 8 + rz) * HW + (size_t)tid * 4);
        __builtin_amdgcn_sched_barrier(0);

        #pragma unroll
        for (int g = 0; g < 2; ++g) {
            // x-pool (inside float4) + z-pool (4 planes, in-thread)
            float s = 0.f;
            #pragma unroll
            for (int j = 0; j < 4; ++j) {
                const float4 t = v[g * 4 + j];
                s += (t.x + t.y) + (t.z + t.w);
            }
            // y-pool: the 4-row y-group is exactly this wave
            s += __shfl_xor(s, 16);
            s += __shfl_xor(s, 32);
            if (lane < 16) {
                const int zo  = slab * 4 + h * 2 + g;
                const int row = ((b * 16 + zo) * 16 + wv) * 16 + lane;
                dst[(size_t)row * C + c] = s * (1.0f / 64.0f);
            }
        }
    }
}

// ---------------------------------------------------------------------------
// Kernel 2: normalize + three 32x32 Grams. 256 blocks x 256 threads,
// 32 rows/block. Row norms computed during staging via 8-lane shfl
// reduction (8 threads stage one row); normalized rows land in LDS
// (pitch 36: conflict-free b128 reads, 16B-aligned). Thread t owns
// (k = t>>3, l = (t&7)*4 ..+3) of all three Grams; atomicAdd into
// NPART spread copies.
// ---------------------------------------------------------------------------
__global__ __launch_bounds__(256) void gram_kernel(
    const float* __restrict__ A, const float* __restrict__ B,
    float* __restrict__ G)
{
    const int tid = threadIdx.x;
    const int rl  = tid >> 3;        // 0..31 local row
    const int f4  = tid & 7;         // float4 column index

    __shared__ float As[32][36];
    __shared__ float Bs[32][36];

    const int r = blockIdx.x * 32 + rl;
    float4 va = *reinterpret_cast<const float4*>(A + (size_t)r * C + f4 * 4);
    float4 vb = *reinterpret_cast<const float4*>(B + (size_t)r * C + f4 * 4);

    // row sum-of-squares across the 8 staging threads of this row
    float ssa = va.x * va.x + va.y * va.y + va.z * va.z + va.w * va.w;
    float ssb = vb.x * vb.x + vb.y * vb.y + vb.z * vb.z + vb.w * vb.w;
    #pragma unroll
    for (int off = 1; off < 8; off <<= 1) {
        ssa += __shfl_xor(ssa, off);
        ssb += __shfl_xor(ssb, off);
    }
    const float inva = 1.0f / fmaxf(sqrtf(ssa), 1e-8f);
    const float invb = 1.0f / fmaxf(sqrtf(ssb), 1e-8f);
    va.x *= inva; va.y *= inva; va.z *= inva; va.w *= inva;
    vb.x *= invb; vb.y *= invb; vb.z *= invb; vb.w *= invb;
    *reinterpret_cast<float4*>(&As[rl][f4 * 4]) = va;   // 144B pitch: 16B-aligned
    *reinterpret_cast<float4*>(&Bs[rl][f4 * 4]) = vb;
    __syncthreads();

    const int k  = tid >> 3;          // 0..31
    const int l4 = (tid & 7) * 4;     // 0,4,...,28
    float gaa[4] = {0.f, 0.f, 0.f, 0.f};
    float gab[4] = {0.f, 0.f, 0.f, 0.f};
    float gbb[4] = {0.f, 0.f, 0.f, 0.f};

    #pragma unroll
    for (int i = 0; i < 32; ++i) {
        const float a_k = As[i][k];
        const float b_k = Bs[i][k];
        const float4 a_l = *reinterpret_cast<const float4*>(&As[i][l4]);
        const float4 b_l = *reinterpret_cast<const float4*>(&Bs[i][l4]);
        gaa[0] += a_k * a_l.x;  gaa[1] += a_k * a_l.y;
        gaa[2] += a_k * a_l.z;  gaa[3] += a_k * a_l.w;
        gab[0] += a_k * b_l.x;  gab[1] += a_k * b_l.y;
        gab[2] += a_k * b_l.z;  gab[3] += a_k * b_l.w;
        gbb[0] += b_k * b_l.x;  gbb[1] += b_k * b_l.y;
        gbb[2] += b_k * b_l.z;  gbb[3] += b_k * b_l.w;
    }

    float* Gp = G + (size_t)(blockIdx.x & (NPART - 1)) * 3072;
    #pragma unroll
    for (int j = 0; j < 4; ++j) {
        atomicAdd(&Gp[       k * C + l4 + j], gaa[j]);
        atomicAdd(&Gp[1024 + k * C + l4 + j], gab[j]);
        atomicAdd(&Gp[2048 + k * C + l4 + j], gbb[j]);
    }
}

// ---------------------------------------------------------------------------
// Kernel 3: loss = (sum Gaa² - 2 sum Gab² + sum Gbb²) / N²
// (sum NPART parts per entry BEFORE squaring).
// ---------------------------------------------------------------------------
__global__ __launch_bounds__(1024) void finalize_kernel(
    const float* __restrict__ G, float* __restrict__ out)
{
    const int t = threadIdx.x;
    float gaa = 0.f, gab = 0.f, gbb = 0.f;
    #pragma unroll
    for (int p = 0; p < NPART; ++p) {
        gaa += G[p * 3072 + t];
        gab += G[p * 3072 + 1024 + t];
        gbb += G[p * 3072 + 2048 + t];
    }
    float v = gaa * gaa + gbb * gbb - 2.f * gab * gab;

    __shared__ float red[16];
    #pragma unroll
    for (int off = 32; off > 0; off >>= 1) v += __shfl_down(v, off);
    if ((t & 63) == 0) red[t >> 6] = v;
    __syncthreads();
    if (t < 16) {
        float w = red[t];
        #pragma unroll
        for (int off = 8; off > 0; off >>= 1) w += __shfl_down(w, off);
        if (t == 0) out[0] = w / ((float)NROW * (float)NROW);
    }
}

extern "C" void kernel_launch(void* const* d_in, const int* in_sizes, int n_in,
                              void* d_out, int out_size, void* d_ws, size_t ws_size,
                              hipStream_t stream) {
    const float* p1 = (const float*)d_in[0];
    const float* p2 = (const float*)d_in[1];
    float* out = (float*)d_out;

    float* A = (float*)d_ws;                    // 8192*32 floats = 1 MiB
    float* B = A + (size_t)NROW * C;            // 1 MiB
    float* G = B + (size_t)NROW * C;            // NPART*3072 floats = 192 KiB

    hipMemsetAsync(G, 0, NPART * 3072 * sizeof(float), stream);

    pool_kernel<<<512, 1024, 0, stream>>>(p1, p2, A, B);
    gram_kernel<<<256, 256, 0, stream>>>(A, B, G);
    finalize_kernel<<<1, 1024, 0, stream>>>(G, out);
}

// Round 5
// 155.987 us; speedup vs baseline: 1.0386x; 1.0386x over previous
//
#include <hip/hip_runtime.h>

// Problem: p1,p2 : (B=2, C=32, D=H=W=64) fp32. Pool 4x4x4 -> S=16.
// N = B*S^3 = 8192 rows of C=32. loss = ||A Aᵀ - B Bᵀ||_F² / N²
//           = (||AᵀA||² - 2||AᵀB||² + ||BᵀB||²) / N²  with 32x32 Grams only.
//
// v6: TWO dispatches, no memset, no atomics-into-workspace.
//  - Round-4 lesson: hipLaunchCooperativeKernel silently fails under the
//    graph-capture harness (output stayed 0) -> single-dispatch is illegal.
//  - Rounds 0-3: pool phase is at its service-rate roofline (268 MB logical
//    in ~43 us = 6.2 TB/s HBM+L3 combined; invariant across 4 structures).
//  - Dispatch boundaries cost ~10 us -> drop the memset by replacing
//    atomicAdd-into-G with per-block plain-stored partials P[bid][3072];
//    finalize sums slots (6.3 MB, coalesced), squares, atomicAdds 1 scalar
//    per block into out (harness zeroes out before the check launch).

#define HW    4096      // 64*64
#define DHW   262144    // 64*64*64
#define NROW  8192
#define C     32
#define NBLK  512       // fused-kernel blocks (one per (sel,b,zo,yo) x-row set)
#define FBLK  16        // finalize blocks (64 Gram entries each)

// ---------------------------------------------------------------------------
// Kernel 1: fused pool + normalize + Gram partial (round-2 verified body,
// tail changed: plain-store partial instead of atomicAdd).
// grid = 512 : (b,zo,yo). 1024 threads = 16 waves.
// Wave wv loads channels {2wv, 2wv+1} of BOTH inputs (contiguous 1KiB
// wave-lines); 16 pooled rows per block.
// ---------------------------------------------------------------------------
__global__ __launch_bounds__(1024) void fused_pool_gram_kernel(
    const float* __restrict__ p1, const float* __restrict__ p2,
    float* __restrict__ P)      // P[NBLK][3072]
{
    const int bid = blockIdx.x;
    const int yo = bid & 15;
    const int zo = (bid >> 4) & 15;
    const int b  = bid >> 8;

    const int tid  = threadIdx.x;
    const int wv   = tid >> 6;       // 0..15
    const int lane = tid & 63;
    const int dy   = lane >> 4;      // 0..3
    const int x4   = lane & 15;      // 0..15 (float4 index along W)

    __shared__ float pa[C][17];      // +1 pad: conflict-free column reads
    __shared__ float pb[C][17];
    __shared__ float inva[16];
    __shared__ float invb[16];

    const size_t sp_off = (size_t)(4 * zo) * HW + (size_t)(4 * yo + dy) * 64 + 4 * x4;

    float4 va[2][4], vb[2][4];
    #pragma unroll
    for (int cc = 0; cc < 2; ++cc) {
        const int c = wv * 2 + cc;
        const float* basea = p1 + (size_t)(b * C + c) * DHW + sp_off;
        const float* baseb = p2 + (size_t)(b * C + c) * DHW + sp_off;
        #pragma unroll
        for (int dz = 0; dz < 4; ++dz) {
            va[cc][dz] = *reinterpret_cast<const float4*>(basea + dz * HW);
            vb[cc][dz] = *reinterpret_cast<const float4*>(baseb + dz * HW);
        }
    }

    #pragma unroll
    for (int cc = 0; cc < 2; ++cc) {
        float sa = 0.f, sb = 0.f;
        #pragma unroll
        for (int dz = 0; dz < 4; ++dz) {
            sa += (va[cc][dz].x + va[cc][dz].y) + (va[cc][dz].z + va[cc][dz].w);
            sb += (vb[cc][dz].x + vb[cc][dz].y) + (vb[cc][dz].z + vb[cc][dz].w);
        }
        sa += __shfl_xor(sa, 16);  sa += __shfl_xor(sa, 32);
        sb += __shfl_xor(sb, 16);  sb += __shfl_xor(sb, 32);
        if (lane < 16) {
            pa[wv * 2 + cc][lane] = sa * (1.0f / 64.0f);
            pb[wv * 2 + cc][lane] = sb * (1.0f / 64.0f);
        }
    }
    __syncthreads();

    // per-row inverse norms (rows = the 16 x-positions)
    if (tid < 32) {
        const int x = tid & 15;
        float ss = 0.f;
        if (tid < 16) {
            #pragma unroll
            for (int c2 = 0; c2 < C; ++c2) { const float v = pa[c2][x]; ss += v * v; }
            inva[x] = 1.0f / fmaxf(sqrtf(ss), 1e-8f);
        } else {
            #pragma unroll
            for (int c2 = 0; c2 < C; ++c2) { const float v = pb[c2][x]; ss += v * v; }
            invb[x] = 1.0f / fmaxf(sqrtf(ss), 1e-8f);
        }
    }
    __syncthreads();

    // normalize in place (1024 threads cover 2 x 32 x 16 entries)
    {
        const int sel = tid >> 9;        // 0: pa, 1: pb
        const int c   = (tid >> 4) & 31;
        const int x   = tid & 15;
        if (sel == 0) pa[c][x] *= inva[x];
        else          pb[c][x] *= invb[x];
    }
    __syncthreads();

    // Gram partials over this block's 16 rows: thread t owns (k,l)
    const int k = tid >> 5;              // 0..31
    const int l = tid & 31;              // 0..31
    float gaa = 0.f, gab = 0.f, gbb = 0.f;
    #pragma unroll
    for (int x = 0; x < 16; ++x) {
        const float ak = pa[k][x];       // same addr in half-wave: broadcast
        const float al = pa[l][x];       // stride-17: conflict-free
        const float bk = pb[k][x];
        const float bl = pb[l][x];
        gaa += ak * al;
        gab += ak * bl;
        gbb += bk * bl;
    }

    // plain-store this block's partial (coalesced, no init required)
    float* Pb = P + (size_t)bid * 3072;
    Pb[       tid] = gaa;    // tid == k*32+l
    Pb[1024 + tid] = gab;
    Pb[2048 + tid] = gbb;
}

// ---------------------------------------------------------------------------
// Kernel 2: finalize. 16 blocks x 1024 threads; block j owns Gram entries
// e in [64j, 64j+64). Thread (g = t>>6, eoff = t&63) sums 32 slots for its
// entry's three matrices; LDS-reduce the 16 slot-groups; square-combine;
// one atomicAdd per block into out (harness zeroes out before the check).
// ---------------------------------------------------------------------------
__global__ __launch_bounds__(1024) void finalize_kernel(
    const float* __restrict__ P, float* __restrict__ out)
{
    const int t    = threadIdx.x;
    const int eoff = t & 63;
    const int e    = blockIdx.x * 64 + eoff;
    const int g    = t >> 6;         // 0..15 slot-group

    float s0 = 0.f, s1 = .0f, s2 = 0.f;
    #pragma unroll 8
    for (int s = g * 32; s < g * 32 + 32; ++s) {
        const float* Ps = P + (size_t)s * 3072;
        s0 += Ps[e];                 // 64 consecutive lanes -> 256B coalesced
        s1 += Ps[1024 + e];
        s2 += Ps[2048 + e];
    }

    __shared__ float sh[3][16][64];
    sh[0][g][eoff] = s0;
    sh[1][g][eoff] = s1;
    sh[2][g][eoff] = s2;
    __syncthreads();

    if (t < 64) {
        float gaa = 0.f, gab = 0.f, gbb = 0.f;
        #pragma unroll
        for (int gg = 0; gg < 16; ++gg) {
            gaa += sh[0][gg][t];
            gab += sh[1][gg][t];
            gbb += sh[2][gg][t];
        }
        float v = gaa * gaa + gbb * gbb - 2.f * gab * gab;
        #pragma unroll
        for (int off = 32; off > 0; off >>= 1) v += __shfl_down(v, off);
        if (t == 0)
            atomicAdd(out, v / ((float)NROW * (float)NROW));
    }
}

extern "C" void kernel_launch(void* const* d_in, const int* in_sizes, int n_in,
                              void* d_out, int out_size, void* d_ws, size_t ws_size,
                              hipStream_t stream) {
    const float* p1 = (const float*)d_in[0];
    const float* p2 = (const float*)d_in[1];
    float* out = (float*)d_out;
    float* P   = (float*)d_ws;   // NBLK * 3072 floats = 6 MiB

    fused_pool_gram_kernel<<<NBLK, 1024, 0, stream>>>(p1, p2, P);
    finalize_kernel<<<FBLK, 1024, 0, stream>>>(P, out);
}